// Round 2
// baseline (2459.398 us; speedup 1.0000x reference)
//
#include <hip/hip_runtime.h>

#define DIM 512
#define N_ROWS 16384
#define K_CODES 8192
#define BK 32
#define TM 128
#define TN 128
#define NG (K_CODES / TN)               // 64 code groups
#define OUT_ELEMS (N_ROWS * DIM)        // 8388608
#define MARGIN 0.0625f

typedef __bf16 bf16;
typedef __bf16 bf16x8 __attribute__((ext_vector_type(8)));
typedef float f32x4 __attribute__((ext_vector_type(4)));

// ---------------- kernel 0: fp32 -> (hi, lo) bf16 split ----------------
__global__ __launch_bounds__(256) void vq_split_kernel(const float* __restrict__ src,
                                                       bf16* __restrict__ hi,
                                                       bf16* __restrict__ lo) {
  int i = (blockIdx.x * 256 + threadIdx.x) * 8;
  float4 v0 = *(const float4*)(src + i);
  float4 v1 = *(const float4*)(src + i + 4);
  float f[8] = {v0.x, v0.y, v0.z, v0.w, v1.x, v1.y, v1.z, v1.w};
  bf16x8 h, l;
  #pragma unroll
  for (int j = 0; j < 8; ++j) {
    bf16 hj = (bf16)f[j];              // RNE
    h[j] = hj;
    l[j] = (bf16)(f[j] - (float)hj);   // exact residual, then RNE
  }
  *(bf16x8*)(hi + i) = h;
  *(bf16x8*)(lo + i) = l;
}

// ---------------- kernel 1: per-code squared norms (fp32) ----------------
__global__ __launch_bounds__(256) void vq_enorm_kernel(const float* __restrict__ emb,
                                                       float* __restrict__ enorm) {
  int gid  = blockIdx.x * 256 + threadIdx.x;
  int code = gid >> 6;
  int lane = gid & 63;
  const float4* p = (const float4*)(emb + code * DIM + lane * 8);
  float4 a = p[0], b = p[1];
  float s = a.x*a.x + a.y*a.y + a.z*a.z + a.w*a.w
          + b.x*b.x + b.y*b.y + b.z*b.z + b.w*b.w;
  #pragma unroll
  for (int off = 32; off > 0; off >>= 1) s += __shfl_down(s, off);
  if (lane == 0) enorm[code] = s;
}

// ---------------- async global->LDS 16B helper ----------------
__device__ __forceinline__ void gl2lds16(const bf16* g, bf16* l) {
  __builtin_amdgcn_global_load_lds((const __attribute__((address_space(1))) unsigned int*)g,
                                   (__attribute__((address_space(3))) unsigned int*)l,
                                   16, 0, 0);
}

__device__ __forceinline__ void top2_merge(float& d1, int& i1, float& d2,
                                           float od1, int oi1, float od2) {
  if (od1 < d1 || (od1 == d1 && oi1 < i1)) {
    d2 = fminf(d1, od2);
    d1 = od1; i1 = oi1;
  } else {
    d2 = fminf(d2, od1);
  }
}

// ---------------- kernel 2: 3-term split-bf16 MFMA GEMM + top-2 argmin ----------------
// sim = x_hi.e_hi + x_hi.e_lo + x_lo.e_hi ; dist = ||e||^2 - 2 sim (+||x||^2 const/row)
__global__ __launch_bounds__(256, 2) void vq_argmin_mfma_kernel(
    const bf16* __restrict__ xh, const bf16* __restrict__ xl,
    const bf16* __restrict__ eh, const bf16* __restrict__ el,
    const float* __restrict__ enorm,
    float* __restrict__ cand_d1, int* __restrict__ cand_i1, float* __restrict__ cand_d2) {
  __shared__ __align__(16) bf16 Axh[TM * BK];   // 8 KB each
  __shared__ __align__(16) bf16 Axl[TM * BK];
  __shared__ __align__(16) bf16 Beh[TN * BK];
  __shared__ __align__(16) bf16 Bel[TN * BK];
  __shared__ float red_d1[2][TM];
  __shared__ int   red_i1[2][TM];
  __shared__ float red_d2[2][TM];

  const int tid  = threadIdx.x;
  const int wave = tid >> 6;
  const int lane = tid & 63;
  const int bm = blockIdx.x, bn = blockIdx.y;
  const int wr = (wave >> 1) * 64;   // wave's row offset in tile
  const int wc = (wave & 1) * 64;    // wave's col offset in tile

  // staging: each wave owns one LDS tile; lane -> 16B chunk, 4 lanes/row
  const bf16* gsrc0;
  bf16* ldst;
  {
    const int srow = lane >> 2;           // 0..15
    const int scol = (lane & 3) * 8;      // 0,8,16,24
    if (wave == 0)      { gsrc0 = xh + (size_t)(bm * TM + srow) * DIM + scol; ldst = Axh; }
    else if (wave == 1) { gsrc0 = xl + (size_t)(bm * TM + srow) * DIM + scol; ldst = Axl; }
    else if (wave == 2) { gsrc0 = eh + (size_t)(bn * TN + srow) * DIM + scol; ldst = Beh; }
    else                { gsrc0 = el + (size_t)(bn * TN + srow) * DIM + scol; ldst = Bel; }
  }

  f32x4 acc[4][4];
  #pragma unroll
  for (int i = 0; i < 4; ++i)
    #pragma unroll
    for (int j = 0; j < 4; ++j)
      acc[i][j] = (f32x4){0.f, 0.f, 0.f, 0.f};

  const int fr = lane & 15;   // fragment row/col within 16
  const int fq = lane >> 4;   // k-quad

  for (int k0 = 0; k0 < DIM; k0 += BK) {
    __syncthreads();   // previous iteration's LDS reads complete
    #pragma unroll
    for (int i = 0; i < 8; ++i)
      gl2lds16(gsrc0 + (size_t)i * 16 * DIM + k0, ldst + i * 16 * BK);
    __syncthreads();   // loads drained (vmcnt(0) before barrier)

    bf16x8 ah[4], al[4], bh[4], bl[4];
    #pragma unroll
    for (int f = 0; f < 4; ++f) {
      ah[f] = *(const bf16x8*)&Axh[(wr + f * 16 + fr) * BK + fq * 8];
      al[f] = *(const bf16x8*)&Axl[(wr + f * 16 + fr) * BK + fq * 8];
      bh[f] = *(const bf16x8*)&Beh[(wc + f * 16 + fr) * BK + fq * 8];
      bl[f] = *(const bf16x8*)&Bel[(wc + f * 16 + fr) * BK + fq * 8];
    }
    #pragma unroll
    for (int mf = 0; mf < 4; ++mf)
      #pragma unroll
      for (int nf = 0; nf < 4; ++nf) {
        acc[mf][nf] = __builtin_amdgcn_mfma_f32_16x16x32_bf16(ah[mf], bh[nf], acc[mf][nf], 0, 0, 0);
        acc[mf][nf] = __builtin_amdgcn_mfma_f32_16x16x32_bf16(ah[mf], bl[nf], acc[mf][nf], 0, 0, 0);
        acc[mf][nf] = __builtin_amdgcn_mfma_f32_16x16x32_bf16(al[mf], bh[nf], acc[mf][nf], 0, 0, 0);
      }
  }

  // ---- epilogue: distances + per-row top-2 over this block's 128 cols ----
  float en[4];
  #pragma unroll
  for (int nf = 0; nf < 4; ++nf)
    en[nf] = enorm[bn * TN + wc + nf * 16 + fr];

  #pragma unroll
  for (int mf = 0; mf < 4; ++mf) {
    #pragma unroll
    for (int reg = 0; reg < 4; ++reg) {
      float d1 = 3.4e38f, d2 = 3.4e38f;
      int i1 = 0;
      #pragma unroll
      for (int nf = 0; nf < 4; ++nf) {   // ascending col keeps lowest idx on ties
        float d = en[nf] - 2.0f * acc[mf][nf][reg];
        int ci = bn * TN + wc + nf * 16 + fr;
        if (d < d1) { d2 = d1; d1 = d; i1 = ci; }
        else if (d < d2) { d2 = d; }
      }
      // butterfly over the 16 lanes (same fq) holding this row's 64 cols
      #pragma unroll
      for (int m = 1; m <= 8; m <<= 1) {
        float od1 = __shfl_xor(d1, m, 16);
        int   oi1 = __shfl_xor(i1, m, 16);
        float od2 = __shfl_xor(d2, m, 16);
        top2_merge(d1, i1, d2, od1, oi1, od2);
      }
      if (fr == 0) {
        int row = wr + mf * 16 + fq * 4 + reg;
        red_d1[wave & 1][row] = d1;
        red_i1[wave & 1][row] = i1;
        red_d2[wave & 1][row] = d2;
      }
    }
  }
  __syncthreads();
  if (tid < TM) {
    float d1 = red_d1[0][tid]; int i1 = red_i1[0][tid]; float d2 = red_d2[0][tid];
    top2_merge(d1, i1, d2, red_d1[1][tid], red_i1[1][tid], red_d2[1][tid]);
    size_t o = (size_t)bn * N_ROWS + (size_t)bm * TM + tid;
    cand_d1[o] = d1; cand_i1[o] = i1; cand_d2[o] = d2;
  }
}

// ---------------- kernel 3: merge 64 groups -> idx + ambiguity flag ----------------
__global__ __launch_bounds__(256) void vq_merge2_kernel(
    const float* __restrict__ cd1, const int* __restrict__ ci1, const float* __restrict__ cd2,
    int* __restrict__ idx, int* __restrict__ flag, float* __restrict__ loss_slot) {
  int r = blockIdx.x * 256 + threadIdx.x;
  if (r == 0) *loss_slot = 0.0f;
  float d1 = 3.4e38f, d2 = 3.4e38f;
  int i1 = 0;
  for (int g = 0; g < NG; ++g) {   // ascending g = ascending col blocks
    size_t o = (size_t)g * N_ROWS + r;
    top2_merge(d1, i1, d2, cd1[o], ci1[o], cd2[o]);
  }
  idx[r] = i1;
  flag[r] = (d2 - d1 < MARGIN) ? 1 : 0;
}

// ---------------- kernel 4: exact fp32 rescan for ambiguous rows ----------------
__global__ __launch_bounds__(256) void vq_rescan_kernel(
    const float* __restrict__ x, const float* __restrict__ emb,
    const float* __restrict__ enorm, const int* __restrict__ flag,
    int* __restrict__ idx) {
  int r = blockIdx.x;
  if (!flag[r]) return;
  __shared__ float4 xs[DIM / 4];
  __shared__ float rd[256];
  __shared__ int   ri[256];
  int t = threadIdx.x;
  if (t < 128) xs[t] = ((const float4*)(x + (size_t)r * DIM))[t];
  __syncthreads();
  float bd = 3.4e38f; int bi = 0;
  for (int c = t; c < K_CODES; c += 256) {
    const float4* e4 = (const float4*)(emb + (size_t)c * DIM);
    float s0 = 0.f, s1 = 0.f, s2 = 0.f, s3 = 0.f;
    #pragma unroll 4
    for (int k = 0; k < DIM / 4; ++k) {
      float4 xv = xs[k]; float4 ev = e4[k];
      s0 = fmaf(xv.x, ev.x, s0); s1 = fmaf(xv.y, ev.y, s1);
      s2 = fmaf(xv.z, ev.z, s2); s3 = fmaf(xv.w, ev.w, s3);
    }
    float d = enorm[c] - 2.0f * ((s0 + s1) + (s2 + s3));
    if (d < bd) { bd = d; bi = c; }   // ascending c keeps lowest idx
  }
  rd[t] = bd; ri[t] = bi;
  __syncthreads();
  for (int s = 128; s > 0; s >>= 1) {
    if (t < s) {
      if (rd[t + s] < rd[t] || (rd[t + s] == rd[t] && ri[t + s] < ri[t])) {
        rd[t] = rd[t + s]; ri[t] = ri[t + s];
      }
    }
    __syncthreads();
  }
  if (t == 0) idx[r] = ri[0];
}

// ---------------- kernel 5: gather + outputs + loss ----------------
__global__ __launch_bounds__(256) void vq_gather_kernel(
    const float* __restrict__ x, const float* __restrict__ emb,
    const int* __restrict__ idx,
    float* __restrict__ out, float* __restrict__ quant,
    float* __restrict__ loss_slot) {
  __shared__ float wsum[4];
  const int wave = threadIdx.x >> 6;
  const int lane = threadIdx.x & 63;
  const int row  = blockIdx.x * 4 + wave;
  const int code = idx[row];
  const float4* xp = (const float4*)(x   + (size_t)row  * DIM + lane * 8);
  const float4* ep = (const float4*)(emb + (size_t)code * DIM + lane * 8);
  float s = 0.0f;
  #pragma unroll
  for (int t = 0; t < 2; ++t) {
    float4 xv = xp[t];
    float4 ev = ep[t];
    float dx = ev.x - xv.x, dy = ev.y - xv.y, dz = ev.z - xv.z, dw = ev.w - xv.w;
    s += dx * dx + dy * dy + dz * dz + dw * dw;
    ((float4*)(out   + (size_t)row * DIM + lane * 8))[t] = ev;  // out == quantized (straight-through)
    ((float4*)(quant + (size_t)row * DIM + lane * 8))[t] = ev;
  }
  #pragma unroll
  for (int off = 32; off > 0; off >>= 1) s += __shfl_down(s, off);
  if (lane == 0) wsum[wave] = s;
  __syncthreads();
  if (threadIdx.x == 0) {
    float tot = wsum[0] + wsum[1] + wsum[2] + wsum[3];
    atomicAdd(loss_slot, tot * (1.25f / (float)OUT_ELEMS));
  }
}

extern "C" void kernel_launch(void* const* d_in, const int* in_sizes, int n_in,
                              void* d_out, int out_size, void* d_ws, size_t ws_size,
                              hipStream_t stream) {
  const float* x   = (const float*)d_in[0];   // [16384, 512]
  const float* emb = (const float*)d_in[1];   // [8192, 512]
  float* out   = (float*)d_out;
  float* quant = out + OUT_ELEMS;
  float* loss  = out + 2 * OUT_ELEMS;

  char* ws = (char*)d_ws;
  bf16*  xh    = (bf16*)(ws);                          // 16.78 MB
  bf16*  xl    = (bf16*)(ws + 16777216);               // 16.78 MB
  bf16*  eh    = (bf16*)(ws + 33554432);               //  8.39 MB
  bf16*  el    = (bf16*)(ws + 41943040);               //  8.39 MB
  float* enorm = (float*)(ws + 50331648);              // 32 KB
  float* cd1   = (float*)(ws + 50364416);              // 4 MB
  int*   ci1   = (int*)  (ws + 54558720);              // 4 MB
  float* cd2   = (float*)(ws + 58753024);              // 4 MB
  int*   idx   = (int*)  (ws + 62947328);              // 64 KB
  int*   flag  = (int*)  (ws + 63012864);              // 64 KB

  vq_split_kernel<<<OUT_ELEMS / (8 * 256), 256, 0, stream>>>(x, xh, xl);           // 4096 blocks
  vq_split_kernel<<<(K_CODES * DIM) / (8 * 256), 256, 0, stream>>>(emb, eh, el);   // 2048 blocks
  vq_enorm_kernel<<<K_CODES * 64 / 256, 256, 0, stream>>>(emb, enorm);
  vq_argmin_mfma_kernel<<<dim3(N_ROWS / TM, K_CODES / TN), 256, 0, stream>>>(
      xh, xl, eh, el, enorm, cd1, ci1, cd2);
  vq_merge2_kernel<<<N_ROWS / 256, 256, 0, stream>>>(cd1, ci1, cd2, idx, flag, loss);
  vq_rescan_kernel<<<N_ROWS, 256, 0, stream>>>(x, emb, enorm, flag, idx);
  vq_gather_kernel<<<N_ROWS / 4, 256, 0, stream>>>(x, emb, idx, out, quant, loss);
}

// Round 3
// 662.734 us; speedup vs baseline: 3.7110x; 3.7110x over previous
//
#include <hip/hip_runtime.h>

#define DIM 512
#define N_ROWS 16384
#define K_CODES 8192
#define BK 32
#define TM 128
#define TN 128
#define NG (K_CODES / TN)               // 64 code groups
#define OUT_ELEMS (N_ROWS * DIM)        // 8388608
#define MARGIN 0.01f
#define RESCAN_CHUNK 1024
#define RESCAN_NCHUNK (K_CODES / RESCAN_CHUNK)  // 8

typedef __bf16 bf16;
typedef __bf16 bf16x8 __attribute__((ext_vector_type(8)));
typedef float f32x4 __attribute__((ext_vector_type(4)));

// monotone float->uint map: min on packed == (min dist, then min idx)
__device__ __forceinline__ unsigned long long pack_di(float d, int i) {
  unsigned u = __float_as_uint(d);
  u = (u & 0x80000000u) ? ~u : (u | 0x80000000u);
  return ((unsigned long long)u << 32) | (unsigned)i;
}

// ---------------- kernel 0: fp32 -> (hi, lo) bf16 split ----------------
__global__ __launch_bounds__(256) void vq_split_kernel(const float* __restrict__ src,
                                                       bf16* __restrict__ hi,
                                                       bf16* __restrict__ lo) {
  int i = (blockIdx.x * 256 + threadIdx.x) * 8;
  float4 v0 = *(const float4*)(src + i);
  float4 v1 = *(const float4*)(src + i + 4);
  float f[8] = {v0.x, v0.y, v0.z, v0.w, v1.x, v1.y, v1.z, v1.w};
  bf16x8 h, l;
  #pragma unroll
  for (int j = 0; j < 8; ++j) {
    bf16 hj = (bf16)f[j];              // RNE
    h[j] = hj;
    l[j] = (bf16)(f[j] - (float)hj);   // exact residual, then RNE
  }
  *(bf16x8*)(hi + i) = h;
  *(bf16x8*)(lo + i) = l;
}

// ---------------- kernel 1: per-code squared norms (fp32) + counter zero ----------------
__global__ __launch_bounds__(256) void vq_enorm_kernel(const float* __restrict__ emb,
                                                       float* __restrict__ enorm,
                                                       int* __restrict__ counter) {
  int gid  = blockIdx.x * 256 + threadIdx.x;
  if (gid == 0) *counter = 0;
  int code = gid >> 6;
  int lane = gid & 63;
  const float4* p = (const float4*)(emb + code * DIM + lane * 8);
  float4 a = p[0], b = p[1];
  float s = a.x*a.x + a.y*a.y + a.z*a.z + a.w*a.w
          + b.x*b.x + b.y*b.y + b.z*b.z + b.w*b.w;
  #pragma unroll
  for (int off = 32; off > 0; off >>= 1) s += __shfl_down(s, off);
  if (lane == 0) enorm[code] = s;
}

// ---------------- async global->LDS 16B helper ----------------
__device__ __forceinline__ void gl2lds16(const bf16* g, bf16* l) {
  __builtin_amdgcn_global_load_lds((const __attribute__((address_space(1))) unsigned int*)g,
                                   (__attribute__((address_space(3))) unsigned int*)l,
                                   16, 0, 0);
}

__device__ __forceinline__ void top2_merge(float& d1, int& i1, float& d2,
                                           float od1, int oi1, float od2) {
  if (od1 < d1 || (od1 == d1 && oi1 < i1)) {
    d2 = fminf(d1, od2);
    d1 = od1; i1 = oi1;
  } else {
    d2 = fminf(d2, od1);
  }
}

// ---------------- kernel 2: 3-term split-bf16 MFMA GEMM + top-2 argmin ----------------
// sim = x_hi.e_hi + x_hi.e_lo + x_lo.e_hi ; dist = ||e||^2 - 2 sim (+||x||^2 const/row)
__global__ __launch_bounds__(256, 2) void vq_argmin_mfma_kernel(
    const bf16* __restrict__ xh, const bf16* __restrict__ xl,
    const bf16* __restrict__ eh, const bf16* __restrict__ el,
    const float* __restrict__ enorm,
    float* __restrict__ cand_d1, int* __restrict__ cand_i1, float* __restrict__ cand_d2) {
  __shared__ __align__(16) bf16 Axh[TM * BK];   // 8 KB each
  __shared__ __align__(16) bf16 Axl[TM * BK];
  __shared__ __align__(16) bf16 Beh[TN * BK];
  __shared__ __align__(16) bf16 Bel[TN * BK];
  __shared__ float red_d1[2][TM];
  __shared__ int   red_i1[2][TM];
  __shared__ float red_d2[2][TM];

  const int tid  = threadIdx.x;
  const int wave = tid >> 6;
  const int lane = tid & 63;
  const int bm = blockIdx.x, bn = blockIdx.y;
  const int wr = (wave >> 1) * 64;   // wave's row offset in tile
  const int wc = (wave & 1) * 64;    // wave's col offset in tile

  // staging: each wave owns one LDS tile; lane -> 16B chunk, 4 lanes/row
  const bf16* gsrc0;
  bf16* ldst;
  {
    const int srow = lane >> 2;           // 0..15
    const int scol = (lane & 3) * 8;      // 0,8,16,24
    if (wave == 0)      { gsrc0 = xh + (size_t)(bm * TM + srow) * DIM + scol; ldst = Axh; }
    else if (wave == 1) { gsrc0 = xl + (size_t)(bm * TM + srow) * DIM + scol; ldst = Axl; }
    else if (wave == 2) { gsrc0 = eh + (size_t)(bn * TN + srow) * DIM + scol; ldst = Beh; }
    else                { gsrc0 = el + (size_t)(bn * TN + srow) * DIM + scol; ldst = Bel; }
  }

  f32x4 acc[4][4];
  #pragma unroll
  for (int i = 0; i < 4; ++i)
    #pragma unroll
    for (int j = 0; j < 4; ++j)
      acc[i][j] = (f32x4){0.f, 0.f, 0.f, 0.f};

  const int fr = lane & 15;   // fragment row/col within 16
  const int fq = lane >> 4;   // k-quad

  for (int k0 = 0; k0 < DIM; k0 += BK) {
    __syncthreads();   // previous iteration's LDS reads complete
    #pragma unroll
    for (int i = 0; i < 8; ++i)
      gl2lds16(gsrc0 + (size_t)i * 16 * DIM + k0, ldst + i * 16 * BK);
    __syncthreads();   // loads drained (vmcnt(0) before barrier)

    bf16x8 ah[4], al[4], bh[4], bl[4];
    #pragma unroll
    for (int f = 0; f < 4; ++f) {
      ah[f] = *(const bf16x8*)&Axh[(wr + f * 16 + fr) * BK + fq * 8];
      al[f] = *(const bf16x8*)&Axl[(wr + f * 16 + fr) * BK + fq * 8];
      bh[f] = *(const bf16x8*)&Beh[(wc + f * 16 + fr) * BK + fq * 8];
      bl[f] = *(const bf16x8*)&Bel[(wc + f * 16 + fr) * BK + fq * 8];
    }
    #pragma unroll
    for (int mf = 0; mf < 4; ++mf)
      #pragma unroll
      for (int nf = 0; nf < 4; ++nf) {
        acc[mf][nf] = __builtin_amdgcn_mfma_f32_16x16x32_bf16(ah[mf], bh[nf], acc[mf][nf], 0, 0, 0);
        acc[mf][nf] = __builtin_amdgcn_mfma_f32_16x16x32_bf16(ah[mf], bl[nf], acc[mf][nf], 0, 0, 0);
        acc[mf][nf] = __builtin_amdgcn_mfma_f32_16x16x32_bf16(al[mf], bh[nf], acc[mf][nf], 0, 0, 0);
      }
  }

  // ---- epilogue: distances + per-row top-2 over this block's 128 cols ----
  float en[4];
  #pragma unroll
  for (int nf = 0; nf < 4; ++nf)
    en[nf] = enorm[bn * TN + wc + nf * 16 + fr];

  #pragma unroll
  for (int mf = 0; mf < 4; ++mf) {
    #pragma unroll
    for (int reg = 0; reg < 4; ++reg) {
      float d1 = 3.4e38f, d2 = 3.4e38f;
      int i1 = 0;
      #pragma unroll
      for (int nf = 0; nf < 4; ++nf) {   // ascending col keeps lowest idx on ties
        float d = en[nf] - 2.0f * acc[mf][nf][reg];
        int ci = bn * TN + wc + nf * 16 + fr;
        if (d < d1) { d2 = d1; d1 = d; i1 = ci; }
        else if (d < d2) { d2 = d; }
      }
      // butterfly over the 16 lanes (same fq) holding this row's 64 cols
      #pragma unroll
      for (int m = 1; m <= 8; m <<= 1) {
        float od1 = __shfl_xor(d1, m, 16);
        int   oi1 = __shfl_xor(i1, m, 16);
        float od2 = __shfl_xor(d2, m, 16);
        top2_merge(d1, i1, d2, od1, oi1, od2);
      }
      if (fr == 0) {
        int row = wr + mf * 16 + fq * 4 + reg;
        red_d1[wave & 1][row] = d1;
        red_i1[wave & 1][row] = i1;
        red_d2[wave & 1][row] = d2;
      }
    }
  }
  __syncthreads();
  if (tid < TM) {
    float d1 = red_d1[0][tid]; int i1 = red_i1[0][tid]; float d2 = red_d2[0][tid];
    top2_merge(d1, i1, d2, red_d1[1][tid], red_i1[1][tid], red_d2[1][tid]);
    size_t o = (size_t)bn * N_ROWS + (size_t)bm * TM + tid;
    cand_d1[o] = d1; cand_i1[o] = i1; cand_d2[o] = d2;
  }
}

// ---------------- kernel 3: merge 64 groups -> idx, flag + compacted work list ----------------
__global__ __launch_bounds__(256) void vq_merge2_kernel(
    const float* __restrict__ cd1, const int* __restrict__ ci1, const float* __restrict__ cd2,
    int* __restrict__ idx, int* __restrict__ flag,
    int* __restrict__ counter, int* __restrict__ flagged,
    unsigned long long* __restrict__ packed,
    float* __restrict__ loss_slot) {
  int r = blockIdx.x * 256 + threadIdx.x;
  if (r == 0) *loss_slot = 0.0f;
  float d1 = 3.4e38f, d2 = 3.4e38f;
  int i1 = 0;
  for (int g = 0; g < NG; ++g) {   // ascending g = ascending col blocks
    size_t o = (size_t)g * N_ROWS + r;
    top2_merge(d1, i1, d2, cd1[o], ci1[o], cd2[o]);
  }
  idx[r] = i1;
  int f = (d2 - d1 < MARGIN) ? 1 : 0;
  flag[r] = f;
  if (f) {
    packed[r] = 0xFFFFFFFFFFFFFFFFULL;
    int slot = atomicAdd(counter, 1);
    flagged[slot] = r;
  }
}

// ---------------- kernel 4: exact fp32 rescan, parallel work-queue ----------------
// work item = (flagged row, chunk of 1024 codes); grid-stride; atomicMin on packed
__global__ __launch_bounds__(256) void vq_rescan_kernel(
    const float* __restrict__ x, const float* __restrict__ emb,
    const float* __restrict__ enorm,
    const int* __restrict__ counter, const int* __restrict__ flagged,
    unsigned long long* __restrict__ packed) {
  __shared__ float4 xs[DIM / 4];
  __shared__ float rd[256];
  __shared__ int   ri[256];
  const int t = threadIdx.x;
  const int nitems = counter[0] * RESCAN_NCHUNK;
  for (int item = blockIdx.x; item < nitems; item += gridDim.x) {
    const int r     = flagged[item / RESCAN_NCHUNK];
    const int c0    = (item % RESCAN_NCHUNK) * RESCAN_CHUNK;
    __syncthreads();   // protect xs from previous iteration's readers
    if (t < 128) xs[t] = ((const float4*)(x + (size_t)r * DIM))[t];
    __syncthreads();
    float bd = 3.4e38f; int bi = 0;
    #pragma unroll
    for (int cc = 0; cc < RESCAN_CHUNK / 256; ++cc) {
      int c = c0 + cc * 256 + t;
      const float4* e4 = (const float4*)(emb + (size_t)c * DIM);
      float s0 = 0.f, s1 = 0.f, s2 = 0.f, s3 = 0.f;
      #pragma unroll 4
      for (int k = 0; k < DIM / 4; ++k) {
        float4 xv = xs[k]; float4 ev = e4[k];
        s0 = fmaf(xv.x, ev.x, s0); s1 = fmaf(xv.y, ev.y, s1);
        s2 = fmaf(xv.z, ev.z, s2); s3 = fmaf(xv.w, ev.w, s3);
      }
      float d = enorm[c] - 2.0f * ((s0 + s1) + (s2 + s3));
      if (d < bd || (d == bd && c < bi)) { bd = d; bi = c; }
    }
    rd[t] = bd; ri[t] = bi;
    __syncthreads();
    for (int s = 128; s > 0; s >>= 1) {
      if (t < s) {
        if (rd[t + s] < rd[t] || (rd[t + s] == rd[t] && ri[t + s] < ri[t])) {
          rd[t] = rd[t + s]; ri[t] = ri[t + s];
        }
      }
      __syncthreads();
    }
    if (t == 0) atomicMin(&packed[r], pack_di(rd[0], ri[0]));
  }
}

// ---------------- kernel 5: gather + outputs + loss ----------------
__global__ __launch_bounds__(256) void vq_gather_kernel(
    const float* __restrict__ x, const float* __restrict__ emb,
    const int* __restrict__ idx, const int* __restrict__ flag,
    const unsigned long long* __restrict__ packed,
    float* __restrict__ out, float* __restrict__ quant,
    float* __restrict__ loss_slot) {
  __shared__ float wsum[4];
  const int wave = threadIdx.x >> 6;
  const int lane = threadIdx.x & 63;
  const int row  = blockIdx.x * 4 + wave;
  const int code = flag[row] ? (int)(packed[row] & 0xFFFFFFFFu) : idx[row];
  const float4* xp = (const float4*)(x   + (size_t)row  * DIM + lane * 8);
  const float4* ep = (const float4*)(emb + (size_t)code * DIM + lane * 8);
  float s = 0.0f;
  #pragma unroll
  for (int t = 0; t < 2; ++t) {
    float4 xv = xp[t];
    float4 ev = ep[t];
    float dx = ev.x - xv.x, dy = ev.y - xv.y, dz = ev.z - xv.z, dw = ev.w - xv.w;
    s += dx * dx + dy * dy + dz * dz + dw * dw;
    ((float4*)(out   + (size_t)row * DIM + lane * 8))[t] = ev;  // out == quantized (straight-through)
    ((float4*)(quant + (size_t)row * DIM + lane * 8))[t] = ev;
  }
  #pragma unroll
  for (int off = 32; off > 0; off >>= 1) s += __shfl_down(s, off);
  if (lane == 0) wsum[wave] = s;
  __syncthreads();
  if (threadIdx.x == 0) {
    float tot = wsum[0] + wsum[1] + wsum[2] + wsum[3];
    atomicAdd(loss_slot, tot * (1.25f / (float)OUT_ELEMS));
  }
}

extern "C" void kernel_launch(void* const* d_in, const int* in_sizes, int n_in,
                              void* d_out, int out_size, void* d_ws, size_t ws_size,
                              hipStream_t stream) {
  const float* x   = (const float*)d_in[0];   // [16384, 512]
  const float* emb = (const float*)d_in[1];   // [8192, 512]
  float* out   = (float*)d_out;
  float* quant = out + OUT_ELEMS;
  float* loss  = out + 2 * OUT_ELEMS;

  char* ws = (char*)d_ws;
  bf16*  xh     = (bf16*)(ws);                          // 16.78 MB
  bf16*  xl     = (bf16*)(ws + 16777216);               // 16.78 MB
  bf16*  eh     = (bf16*)(ws + 33554432);               //  8.39 MB
  bf16*  el     = (bf16*)(ws + 41943040);               //  8.39 MB
  float* enorm  = (float*)(ws + 50331648);              // 32 KB
  float* cd1    = (float*)(ws + 50364416);              // 4 MB
  int*   ci1    = (int*)  (ws + 54558720);              // 4 MB
  float* cd2    = (float*)(ws + 58753024);              // 4 MB
  int*   idx    = (int*)  (ws + 62947328);              // 64 KB
  int*   flag   = (int*)  (ws + 63012864);              // 64 KB
  int*   counter= (int*)  (ws + 63078400);              // 4 B (+pad)
  int*   flagged= (int*)  (ws + 63078656);              // 64 KB
  unsigned long long* packed = (unsigned long long*)(ws + 63144192); // 128 KB

  vq_split_kernel<<<OUT_ELEMS / (8 * 256), 256, 0, stream>>>(x, xh, xl);
  vq_split_kernel<<<(K_CODES * DIM) / (8 * 256), 256, 0, stream>>>(emb, eh, el);
  vq_enorm_kernel<<<K_CODES * 64 / 256, 256, 0, stream>>>(emb, enorm, counter);
  vq_argmin_mfma_kernel<<<dim3(N_ROWS / TM, K_CODES / TN), 256, 0, stream>>>(
      xh, xl, eh, el, enorm, cd1, ci1, cd2);
  vq_merge2_kernel<<<N_ROWS / 256, 256, 0, stream>>>(
      cd1, ci1, cd2, idx, flag, counter, flagged, packed, loss);
  vq_rescan_kernel<<<2048, 256, 0, stream>>>(x, emb, enorm, counter, flagged, packed);
  vq_gather_kernel<<<N_ROWS / 4, 256, 0, stream>>>(x, emb, idx, flag, packed, out, quant, loss);
}

// Round 4
// 627.729 us; speedup vs baseline: 3.9179x; 1.0558x over previous
//
#include <hip/hip_runtime.h>

#define DIM 512
#define N_ROWS 16384
#define K_CODES 8192
#define BK 32
#define TM 128
#define TN 128
#define NG (K_CODES / TN)               // 64 code groups
#define OUT_ELEMS (N_ROWS * DIM)        // 8388608
#define MARGIN 0.01f
#define RESCAN_CHUNK 1024
#define RESCAN_NCHUNK (K_CODES / RESCAN_CHUNK)  // 8

typedef __bf16 bf16;
typedef __bf16 bf16x8 __attribute__((ext_vector_type(8)));
typedef float f32x4 __attribute__((ext_vector_type(4)));

// monotone float->uint map: min on packed == (min dist, then min idx)
__device__ __forceinline__ unsigned long long pack_di(float d, int i) {
  unsigned u = __float_as_uint(d);
  u = (u & 0x80000000u) ? ~u : (u | 0x80000000u);
  return ((unsigned long long)u << 32) | (unsigned)i;
}

// ---------------- kernel 0: fp32 -> (hi, lo) bf16 split (x) ----------------
__global__ __launch_bounds__(256) void vq_split_kernel(const float* __restrict__ src,
                                                       bf16* __restrict__ hi,
                                                       bf16* __restrict__ lo) {
  int i = (blockIdx.x * 256 + threadIdx.x) * 8;
  float4 v0 = *(const float4*)(src + i);
  float4 v1 = *(const float4*)(src + i + 4);
  float f[8] = {v0.x, v0.y, v0.z, v0.w, v1.x, v1.y, v1.z, v1.w};
  bf16x8 h, l;
  #pragma unroll
  for (int j = 0; j < 8; ++j) {
    bf16 hj = (bf16)f[j];              // RNE
    h[j] = hj;
    l[j] = (bf16)(f[j] - (float)hj);   // exact residual, then RNE
  }
  *(bf16x8*)(hi + i) = h;
  *(bf16x8*)(lo + i) = l;
}

// ---------------- kernel 1: emb split + per-code norms + counter zero ----------------
// one wave per code row: 64 lanes x 8 elems = 512
__global__ __launch_bounds__(256) void vq_split_enorm_kernel(
    const float* __restrict__ emb, bf16* __restrict__ eh, bf16* __restrict__ el,
    float* __restrict__ enorm, int* __restrict__ counter) {
  int gid  = blockIdx.x * 256 + threadIdx.x;
  if (gid == 0) *counter = 0;
  int code = gid >> 6;
  int lane = gid & 63;
  size_t off = (size_t)code * DIM + lane * 8;
  float4 v0 = *(const float4*)(emb + off);
  float4 v1 = *(const float4*)(emb + off + 4);
  float f[8] = {v0.x, v0.y, v0.z, v0.w, v1.x, v1.y, v1.z, v1.w};
  bf16x8 h, l;
  float s = 0.0f;
  #pragma unroll
  for (int j = 0; j < 8; ++j) {
    bf16 hj = (bf16)f[j];
    h[j] = hj;
    l[j] = (bf16)(f[j] - (float)hj);
    s = fmaf(f[j], f[j], s);
  }
  *(bf16x8*)(eh + off) = h;
  *(bf16x8*)(el + off) = l;
  #pragma unroll
  for (int o = 32; o > 0; o >>= 1) s += __shfl_down(s, o);
  if (lane == 0) enorm[code] = s;
}

// ---------------- async global->LDS 16B helper ----------------
__device__ __forceinline__ void gl2lds16(const bf16* g, bf16* l) {
  __builtin_amdgcn_global_load_lds((const __attribute__((address_space(1))) unsigned int*)g,
                                   (__attribute__((address_space(3))) unsigned int*)l,
                                   16, 0, 0);
}

__device__ __forceinline__ void top2_merge(float& d1, int& i1, float& d2,
                                           float od1, int oi1, float od2) {
  if (od1 < d1 || (od1 == d1 && oi1 < i1)) {
    d2 = fminf(d1, od2);
    d1 = od1; i1 = oi1;
  } else {
    d2 = fminf(d2, od1);
  }
}

// ---------------- kernel 2: 3-term split-bf16 MFMA GEMM + top-2 argmin ----------------
// sim = x_hi.e_hi + x_hi.e_lo + x_lo.e_hi ; dist = ||e||^2 - 2 sim (+||x||^2 const/row)
// LDS layout XOR-swizzled: 16B chunk c of row r lives at slot c ^ ((r>>1)&3).
// gl2lds dest is wave-uniform-base + lane*16, so the swizzle is applied on the
// GLOBAL SOURCE side (lane l fetches chunk (l&3)^((l>>3)&3) of its row); the
// fragment-read side applies the same XOR. Turns an 8-way granule conflict into
// free 2-way (m136).
__global__ __launch_bounds__(256, 2) void vq_argmin_mfma_kernel(
    const bf16* __restrict__ xh, const bf16* __restrict__ xl,
    const bf16* __restrict__ eh, const bf16* __restrict__ el,
    const float* __restrict__ enorm,
    float* __restrict__ cand_d1, int* __restrict__ cand_i1, float* __restrict__ cand_d2) {
  __shared__ __align__(16) bf16 Axh[TM * BK];   // 8 KB each
  __shared__ __align__(16) bf16 Axl[TM * BK];
  __shared__ __align__(16) bf16 Beh[TN * BK];
  __shared__ __align__(16) bf16 Bel[TN * BK];
  __shared__ float red_d1[2][TM];
  __shared__ int   red_i1[2][TM];
  __shared__ float red_d2[2][TM];

  const int tid  = threadIdx.x;
  const int wave = tid >> 6;
  const int lane = tid & 63;
  const int bm = blockIdx.x, bn = blockIdx.y;
  const int wr = (wave >> 1) * 64;   // wave's row offset in tile
  const int wc = (wave & 1) * 64;    // wave's col offset in tile

  // staging: each wave owns one LDS tile; lane -> 16B chunk, 4 lanes/row.
  // global chunk fetched by lane l: (l&3) ^ ((l>>3)&3)  [source-side swizzle]
  const bf16* gsrc0;
  bf16* ldst;
  {
    const int srow = lane >> 2;                               // 0..15
    const int scol = (((lane & 3) ^ ((lane >> 3) & 3)) * 8);  // swizzled chunk * 8 elems
    if (wave == 0)      { gsrc0 = xh + (size_t)(bm * TM + srow) * DIM + scol; ldst = Axh; }
    else if (wave == 1) { gsrc0 = xl + (size_t)(bm * TM + srow) * DIM + scol; ldst = Axl; }
    else if (wave == 2) { gsrc0 = eh + (size_t)(bn * TN + srow) * DIM + scol; ldst = Beh; }
    else                { gsrc0 = el + (size_t)(bn * TN + srow) * DIM + scol; ldst = Bel; }
  }

  f32x4 acc[4][4];
  #pragma unroll
  for (int i = 0; i < 4; ++i)
    #pragma unroll
    for (int j = 0; j < 4; ++j)
      acc[i][j] = (f32x4){0.f, 0.f, 0.f, 0.f};

  const int fr = lane & 15;   // fragment row/col within 16
  const int fq = lane >> 4;   // k-quad
  // read-side swizzle: slot of k-chunk fq for row (..+fr) = fq ^ ((fr>>1)&3); *8 elems
  const int sw8 = (fq ^ ((fr >> 1) & 3)) * 8;

  for (int k0 = 0; k0 < DIM; k0 += BK) {
    __syncthreads();   // previous iteration's LDS reads complete
    #pragma unroll
    for (int i = 0; i < 8; ++i)
      gl2lds16(gsrc0 + (size_t)i * 16 * DIM + k0, ldst + i * 16 * BK);
    __syncthreads();   // loads drained (vmcnt(0) before barrier)

    bf16x8 ah[4], al[4], bh[4], bl[4];
    #pragma unroll
    for (int f = 0; f < 4; ++f) {
      ah[f] = *(const bf16x8*)&Axh[(wr + f * 16 + fr) * BK + sw8];
      al[f] = *(const bf16x8*)&Axl[(wr + f * 16 + fr) * BK + sw8];
      bh[f] = *(const bf16x8*)&Beh[(wc + f * 16 + fr) * BK + sw8];
      bl[f] = *(const bf16x8*)&Bel[(wc + f * 16 + fr) * BK + sw8];
    }
    #pragma unroll
    for (int mf = 0; mf < 4; ++mf)
      #pragma unroll
      for (int nf = 0; nf < 4; ++nf) {
        acc[mf][nf] = __builtin_amdgcn_mfma_f32_16x16x32_bf16(ah[mf], bh[nf], acc[mf][nf], 0, 0, 0);
        acc[mf][nf] = __builtin_amdgcn_mfma_f32_16x16x32_bf16(ah[mf], bl[nf], acc[mf][nf], 0, 0, 0);
        acc[mf][nf] = __builtin_amdgcn_mfma_f32_16x16x32_bf16(al[mf], bh[nf], acc[mf][nf], 0, 0, 0);
      }
  }

  // ---- epilogue: distances + per-row top-2 over this block's 128 cols ----
  float en[4];
  #pragma unroll
  for (int nf = 0; nf < 4; ++nf)
    en[nf] = enorm[bn * TN + wc + nf * 16 + fr];

  #pragma unroll
  for (int mf = 0; mf < 4; ++mf) {
    #pragma unroll
    for (int reg = 0; reg < 4; ++reg) {
      float d1 = 3.4e38f, d2 = 3.4e38f;
      int i1 = 0;
      #pragma unroll
      for (int nf = 0; nf < 4; ++nf) {   // ascending col keeps lowest idx on ties
        float d = en[nf] - 2.0f * acc[mf][nf][reg];
        int ci = bn * TN + wc + nf * 16 + fr;
        if (d < d1) { d2 = d1; d1 = d; i1 = ci; }
        else if (d < d2) { d2 = d; }
      }
      // butterfly over the 16 lanes (same fq) holding this row's 64 cols
      #pragma unroll
      for (int m = 1; m <= 8; m <<= 1) {
        float od1 = __shfl_xor(d1, m, 16);
        int   oi1 = __shfl_xor(i1, m, 16);
        float od2 = __shfl_xor(d2, m, 16);
        top2_merge(d1, i1, d2, od1, oi1, od2);
      }
      if (fr == 0) {
        int row = wr + mf * 16 + fq * 4 + reg;
        red_d1[wave & 1][row] = d1;
        red_i1[wave & 1][row] = i1;
        red_d2[wave & 1][row] = d2;
      }
    }
  }
  __syncthreads();
  if (tid < TM) {
    float d1 = red_d1[0][tid]; int i1 = red_i1[0][tid]; float d2 = red_d2[0][tid];
    top2_merge(d1, i1, d2, red_d1[1][tid], red_i1[1][tid], red_d2[1][tid]);
    size_t o = (size_t)bn * N_ROWS + (size_t)bm * TM + tid;
    cand_d1[o] = d1; cand_i1[o] = i1; cand_d2[o] = d2;
  }
}

// ---------------- kernel 3: merge 64 groups -> idx, flag + compacted work list ----------------
__global__ __launch_bounds__(256) void vq_merge2_kernel(
    const float* __restrict__ cd1, const int* __restrict__ ci1, const float* __restrict__ cd2,
    int* __restrict__ idx, int* __restrict__ flag,
    int* __restrict__ counter, int* __restrict__ flagged,
    unsigned long long* __restrict__ packed,
    float* __restrict__ loss_slot) {
  int r = blockIdx.x * 256 + threadIdx.x;
  if (r == 0) *loss_slot = 0.0f;
  float d1 = 3.4e38f, d2 = 3.4e38f;
  int i1 = 0;
  for (int g = 0; g < NG; ++g) {   // ascending g = ascending col blocks
    size_t o = (size_t)g * N_ROWS + r;
    top2_merge(d1, i1, d2, cd1[o], ci1[o], cd2[o]);
  }
  idx[r] = i1;
  int f = (d2 - d1 < MARGIN) ? 1 : 0;
  flag[r] = f;
  if (f) {
    packed[r] = 0xFFFFFFFFFFFFFFFFULL;
    int slot = atomicAdd(counter, 1);
    flagged[slot] = r;
  }
}

// ---------------- kernel 4: exact fp32 rescan, parallel work-queue ----------------
__global__ __launch_bounds__(256) void vq_rescan_kernel(
    const float* __restrict__ x, const float* __restrict__ emb,
    const float* __restrict__ enorm,
    const int* __restrict__ counter, const int* __restrict__ flagged,
    unsigned long long* __restrict__ packed) {
  __shared__ float4 xs[DIM / 4];
  __shared__ float rd[256];
  __shared__ int   ri[256];
  const int t = threadIdx.x;
  const int nitems = counter[0] * RESCAN_NCHUNK;
  for (int item = blockIdx.x; item < nitems; item += gridDim.x) {
    const int r     = flagged[item / RESCAN_NCHUNK];
    const int c0    = (item % RESCAN_NCHUNK) * RESCAN_CHUNK;
    __syncthreads();   // protect xs from previous iteration's readers
    if (t < 128) xs[t] = ((const float4*)(x + (size_t)r * DIM))[t];
    __syncthreads();
    float bd = 3.4e38f; int bi = 0;
    #pragma unroll
    for (int cc = 0; cc < RESCAN_CHUNK / 256; ++cc) {
      int c = c0 + cc * 256 + t;
      const float4* e4 = (const float4*)(emb + (size_t)c * DIM);
      float s0 = 0.f, s1 = 0.f, s2 = 0.f, s3 = 0.f;
      #pragma unroll 4
      for (int k = 0; k < DIM / 4; ++k) {
        float4 xv = xs[k]; float4 ev = e4[k];
        s0 = fmaf(xv.x, ev.x, s0); s1 = fmaf(xv.y, ev.y, s1);
        s2 = fmaf(xv.z, ev.z, s2); s3 = fmaf(xv.w, ev.w, s3);
      }
      float d = enorm[c] - 2.0f * ((s0 + s1) + (s2 + s3));
      if (d < bd || (d == bd && c < bi)) { bd = d; bi = c; }
    }
    rd[t] = bd; ri[t] = bi;
    __syncthreads();
    for (int s = 128; s > 0; s >>= 1) {
      if (t < s) {
        if (rd[t + s] < rd[t] || (rd[t + s] == rd[t] && ri[t + s] < ri[t])) {
          rd[t] = rd[t + s]; ri[t] = ri[t + s];
        }
      }
      __syncthreads();
    }
    if (t == 0) atomicMin(&packed[r], pack_di(rd[0], ri[0]));
  }
}

// ---------------- kernel 5: gather + outputs + loss ----------------
__global__ __launch_bounds__(256) void vq_gather_kernel(
    const float* __restrict__ x, const float* __restrict__ emb,
    const int* __restrict__ idx, const int* __restrict__ flag,
    const unsigned long long* __restrict__ packed,
    float* __restrict__ out, float* __restrict__ quant,
    float* __restrict__ loss_slot) {
  __shared__ float wsum[4];
  const int wave = threadIdx.x >> 6;
  const int lane = threadIdx.x & 63;
  const int row  = blockIdx.x * 4 + wave;
  const int code = flag[row] ? (int)(packed[row] & 0xFFFFFFFFu) : idx[row];
  const float4* xp = (const float4*)(x   + (size_t)row  * DIM + lane * 8);
  const float4* ep = (const float4*)(emb + (size_t)code * DIM + lane * 8);
  float s = 0.0f;
  #pragma unroll
  for (int t = 0; t < 2; ++t) {
    float4 xv = xp[t];
    float4 ev = ep[t];
    float dx = ev.x - xv.x, dy = ev.y - xv.y, dz = ev.z - xv.z, dw = ev.w - xv.w;
    s += dx * dx + dy * dy + dz * dz + dw * dw;
    ((float4*)(out   + (size_t)row * DIM + lane * 8))[t] = ev;  // out == quantized (straight-through)
    ((float4*)(quant + (size_t)row * DIM + lane * 8))[t] = ev;
  }
  #pragma unroll
  for (int off = 32; off > 0; off >>= 1) s += __shfl_down(s, off);
  if (lane == 0) wsum[wave] = s;
  __syncthreads();
  if (threadIdx.x == 0) {
    float tot = wsum[0] + wsum[1] + wsum[2] + wsum[3];
    atomicAdd(loss_slot, tot * (1.25f / (float)OUT_ELEMS));
  }
}

extern "C" void kernel_launch(void* const* d_in, const int* in_sizes, int n_in,
                              void* d_out, int out_size, void* d_ws, size_t ws_size,
                              hipStream_t stream) {
  const float* x   = (const float*)d_in[0];   // [16384, 512]
  const float* emb = (const float*)d_in[1];   // [8192, 512]
  float* out   = (float*)d_out;
  float* quant = out + OUT_ELEMS;
  float* loss  = out + 2 * OUT_ELEMS;

  char* ws = (char*)d_ws;
  bf16*  xh     = (bf16*)(ws);                          // 16.78 MB
  bf16*  xl     = (bf16*)(ws + 16777216);               // 16.78 MB
  bf16*  eh     = (bf16*)(ws + 33554432);               //  8.39 MB
  bf16*  el     = (bf16*)(ws + 41943040);               //  8.39 MB
  float* enorm  = (float*)(ws + 50331648);              // 32 KB
  float* cd1    = (float*)(ws + 50364416);              // 4 MB
  int*   ci1    = (int*)  (ws + 54558720);              // 4 MB
  float* cd2    = (float*)(ws + 58753024);              // 4 MB
  int*   idx    = (int*)  (ws + 62947328);              // 64 KB
  int*   flag   = (int*)  (ws + 63012864);              // 64 KB
  int*   counter= (int*)  (ws + 63078400);              // 4 B (+pad)
  int*   flagged= (int*)  (ws + 63078656);              // 64 KB
  unsigned long long* packed = (unsigned long long*)(ws + 63144192); // 128 KB

  vq_split_kernel<<<OUT_ELEMS / (8 * 256), 256, 0, stream>>>(x, xh, xl);
  vq_split_enorm_kernel<<<K_CODES * 64 / 256, 256, 0, stream>>>(emb, eh, el, enorm, counter);
  vq_argmin_mfma_kernel<<<dim3(N_ROWS / TM, K_CODES / TN), 256, 0, stream>>>(
      xh, xl, eh, el, enorm, cd1, ci1, cd2);
  vq_merge2_kernel<<<N_ROWS / 256, 256, 0, stream>>>(
      cd1, ci1, cd2, idx, flag, counter, flagged, packed, loss);
  vq_rescan_kernel<<<2048, 256, 0, stream>>>(x, emb, enorm, counter, flagged, packed);
  vq_gather_kernel<<<N_ROWS / 4, 256, 0, stream>>>(x, emb, idx, flag, packed, out, quant, loss);
}